// Round 16
// baseline (280.914 us; speedup 1.0000x reference)
//
#include <hip/hip_runtime.h>
#include <hip/hip_bf16.h>

// B=64, C=1, H=W=1024, KS=16, F=128, OUT=10, L=4096, K=256
#define B_    64
#define F_    128
#define L_    4096
#define K_    256
#define OUT_  10
#define HW_   (1024 * 1024)
#define WIMG_ 1024

typedef __attribute__((ext_vector_type(8))) short bf16x8;   // MFMA A/B frag
typedef __attribute__((ext_vector_type(4))) float f32x4;    // MFMA C/D frag / NT loads

static __device__ __forceinline__ unsigned short f2bf(float f) {
    return __builtin_bit_cast(unsigned short, __float2bfloat16(f));
}
// non-temporal stream loads (w / dec_w / bias are globally single-use).
// NOTE: __builtin_nontemporal_load requires a native clang vector type,
// not HIP_vector_type (R15 compile failure) -> use f32x4 (ext_vector_type).
static __device__ __forceinline__ f32x4 ldnt4(const float* p) {
    return __builtin_nontemporal_load(reinterpret_cast<const f32x4*>(p));
}
static __device__ __forceinline__ float ldnt1(const float* p) {
    return __builtin_nontemporal_load(p);
}
static __device__ __forceinline__ ushort4 c4v(f32x4 v) {
    return make_ushort4(f2bf(v.x), f2bf(v.y), f2bf(v.z), f2bf(v.w));
}

// ---------------------------------------------------------------------------
// R16 = R14 (structure byte-identical) + NON-TEMPORAL loads on the pure
// streams (w, dec_w, bias) — R15's theory with the compile fix.
// Mechanism: every tensor is globally single-use, so L3 only matters across
// graph replays; NT keeps w's 512MB stream from evicting the 256MB x array
// -> x stays L3-resident, HBM carries only ~535MB.
//  - LDS 48KB: xs[64][128] + wm[128][128] bf16, union'd with ysm -> 3 blk/CU.
//  - w: 2x512B contiguous segs/instr; x: 64B rows (L3-absorbed if theory holds).
//  - 4 waves (m2,n2): acc[2][4]; k-half phases; R14 epilogue/decoder.
// ---------------------------------------------------------------------------
__global__ __launch_bounds__(256, 4)
void lcn_main(const float* __restrict__ x, const float* __restrict__ wgt,
              const float* __restrict__ bias, const float* __restrict__ dec_w,
              float* __restrict__ ws) {
    const int l  = blockIdx.x;
    const int hb = l >> 6, wb = l & 63;
    const int t  = threadIdx.x;
    const int lane = t & 63;
    const int wid  = t >> 6;        // 0..3
    const int ln15 = lane & 15;
    const int kg   = lane >> 4;     // 0..3
    const int m2   = wid >> 1;      // b-half
    const int n2   = wid & 1;       // f-half

    __shared__ union {
        struct { unsigned short xs[B_ * 128]; unsigned short wm[F_ * 128]; } s; // 48 KB
        float ysm[B_][132];          // 33.8 KB (after main loop)
    } u;   // 49152 B -> 3 blocks/CU

    // ---- w staging: per instr 2 contiguous 512B segments (one k-half row) --
    const int lane32 = lane & 31;
    const int fhi    = lane >> 5;        // 0/1: which f of the pair
    auto WSTAGE = [&](int kh) {
        #pragma unroll
        for (int i = 0; i < 16; ++i) {
            const int f = wid * 32 + i * 2 + fhi;
            f32x4 v = ldnt4(wgt + ((size_t)f * L_ + l) * K_ + kh * 128 + lane32 * 4);
            *reinterpret_cast<ushort4*>(
                &u.s.wm[f * 128 + ((lane32 * 4) ^ ((f & 7) << 3))]) = c4v(v);
        }
    };

    // ---- x staging: thread (b = t>>2, cq = t&3); 8 x 64B-row loads/k-half --
    const int sb  = t >> 2;
    const int scq = t & 3;
    const float* xbase = x + (size_t)sb * HW_ + (size_t)(hb * 16) * WIMG_
                           + wb * 16 + scq * 4;
    const int sswz = (sb & 7) << 3;
    auto XSTAGE = [&](int kh) {
        #pragma unroll
        for (int r = 0; r < 8; ++r) {
            f32x4 v = *reinterpret_cast<const f32x4*>(
                xbase + (size_t)(kh * 8 + r) * WIMG_);
            const int kloc = r * 16 + scq * 4;
            *reinterpret_cast<ushort4*>(&u.s.xs[sb * 128 + (kloc ^ sswz)]) = c4v(v);
        }
    };

    // bias preload (NT; 4 scattered dwords, latency hidden under staging)
    float bv[4];
    #pragma unroll
    for (int n = 0; n < 4; ++n)
        bv[n] = ldnt1(bias + (size_t)(n2 * 64 + n * 16 + ln15) * L_ + l);

    f32x4 acc[2][4];
    #pragma unroll
    for (int m = 0; m < 2; ++m)
        #pragma unroll
        for (int n = 0; n < 4; ++n)
            acc[m][n] = (f32x4){0.f, 0.f, 0.f, 0.f};

    #pragma unroll
    for (int kh = 0; kh < 2; ++kh) {
        WSTAGE(kh);
        XSTAGE(kh);
        __syncthreads();   // S1/S3: xs(kh) + wm(kh) ready

        #pragma unroll
        for (int ks = 0; ks < 4; ++ks) {
            const int kloc = ks * 32 + kg * 8;
            bf16x8 a[2], bb[4];
            #pragma unroll
            for (int m = 0; m < 2; ++m) {
                const int b = m2 * 32 + m * 16 + ln15;
                a[m] = *reinterpret_cast<const bf16x8*>(
                    &u.s.xs[b * 128 + (kloc ^ ((b & 7) << 3))]);
            }
            #pragma unroll
            for (int n = 0; n < 4; ++n) {
                const int f = n2 * 64 + n * 16 + ln15;
                bb[n] = *reinterpret_cast<const bf16x8*>(
                    &u.s.wm[f * 128 + (kloc ^ ((f & 7) << 3))]);
            }
            #pragma unroll
            for (int m = 0; m < 2; ++m)
                #pragma unroll
                for (int n = 0; n < 4; ++n)
                    acc[m][n] = __builtin_amdgcn_mfma_f32_16x16x32_bf16(
                        a[m], bb[n], acc[m][n], 0, 0, 0);
        }
        __syncthreads();   // S2/S4: all kh reads done (restage / ysm safe)
    }

    // ---- epilogue: bias + ReLU -> ysm (overlays staging region) ----
    #pragma unroll
    for (int m = 0; m < 2; ++m)
        #pragma unroll
        for (int n = 0; n < 4; ++n)
            #pragma unroll
            for (int r = 0; r < 4; ++r) {
                const int b = m2 * 32 + m * 16 + kg * 4 + r;  // C/D row map
                const int f = n2 * 64 + n * 16 + ln15;        // C/D col map
                u.ysm[b][f] = fmaxf(acc[m][n][r] + bv[n], 0.f);
            }
    __syncthreads();       // S5: ysm ready

    // ---- fused decoder: thread (tx, o) owns b = tx + 16*bi, all 128 f ----
    if (t < 16 * OUT_) {
        const int tx = t & 15;
        const int o  = t >> 4;          // 0..9
        float part[4] = {0.f, 0.f, 0.f, 0.f};
        const float* dwp = dec_w + (size_t)o * ((size_t)F_ * L_) + l;
        #pragma unroll 8
        for (int f = 0; f < F_; ++f) {
            const float dw = ldnt1(dwp + (size_t)f * L_);
            #pragma unroll
            for (int bi = 0; bi < 4; ++bi)
                part[bi] = fmaf(u.ysm[tx + bi * 16][f], dw, part[bi]);
        }
        #pragma unroll
        for (int bi = 0; bi < 4; ++bi)
            ws[((size_t)(tx + bi * 16) * L_ + l) * OUT_ + o] = part[bi];
    }
}

// ---------------------------------------------------------------------------
// Kernel B: reduce ws[b][4096][10] over l, add dec_b.
// ---------------------------------------------------------------------------
__global__ __launch_bounds__(640)
void lcn_reduce(const float* __restrict__ ws, const float* __restrict__ dec_b,
                float* __restrict__ out) {
    const int b = blockIdx.x;
    const int j = threadIdx.x;            // 0..639
    const float* base = ws + (size_t)b * ((size_t)L_ * OUT_);

    float s = 0.f;
    #pragma unroll 8
    for (int i = 0; i < 64; ++i)
        s += base[j + i * (64 * OUT_)];

    __shared__ float lds[640];
    lds[j] = s;
    __syncthreads();

    if (j < OUT_) {
        float tot = dec_b[j];
        #pragma unroll
        for (int lc = 0; lc < 64; ++lc) tot += lds[lc * OUT_ + j];
        out[b * OUT_ + j] = tot;
    }
}

extern "C" void kernel_launch(void* const* d_in, const int* in_sizes, int n_in,
                              void* d_out, int out_size, void* d_ws, size_t ws_size,
                              hipStream_t stream) {
    const float* x     = (const float*)d_in[0];
    const float* wgt   = (const float*)d_in[1];
    const float* bias  = (const float*)d_in[2];
    const float* dec_w = (const float*)d_in[3];
    const float* dec_b = (const float*)d_in[4];
    float* out = (float*)d_out;
    float* wsf = (float*)d_ws;   // 64*4096*10*4 = 10.49 MB

    lcn_main<<<dim3(L_), dim3(256), 0, stream>>>(x, wgt, bias, dec_w, wsf);
    lcn_reduce<<<dim3(B_), dim3(640), 0, stream>>>(wsf, dec_b, out);
}